// Round 3
// baseline (336.032 us; speedup 1.0000x reference)
//
#include <hip/hip_runtime.h>
#include <hip/hip_bf16.h>
#include <math.h>

// Problem constants
#define D      18
#define KCB    4096      // codebook entries
#define NROW   32768     // 8 * 64 * 64
#define KSPLIT 16        // lanes per row-group (split over K)
#define RPT    2         // rows per thread
#define RPB    32        // rows per block = (256/KSPLIT)*RPT
#define KC     128       // K chunk staged in LDS
#define KPTC   8         // k's per thread per chunk (KC/KSPLIT)
#define NCHUNK 32        // KCB / KC
#define PAD    20        // padded row stride in LDS floats (80B, b128-aligned)

#define P100   144.26950408889634f   // 100 * log2(e)
#define LN2f   0.6931471805599453f

#define Q_OFF   0
#define IDX_OFF 589824               // 8*18*64*64
#define SCL_OFF 622592               // + 32768

__device__ __forceinline__ float dot18(float4 a0, float4 a1, float4 a2,
                                       float4 a3, float2 a4,
                                       const float* __restrict__ x)
{
    return x[0]*a0.x + x[1]*a0.y + x[2]*a0.z + x[3]*a0.w
         + x[4]*a1.x + x[5]*a1.y + x[6]*a1.z + x[7]*a1.w
         + x[8]*a2.x + x[9]*a2.y + x[10]*a2.z + x[11]*a2.w
         + x[12]*a3.x + x[13]*a3.y + x[14]*a3.z + x[15]*a3.w
         + x[16]*a4.x + x[17]*a4.y;
}

__global__ __launch_bounds__(256, 4)
void hs_main(const float* __restrict__ x, const float* __restrict__ sp,
             float* __restrict__ out_q, float* __restrict__ out_idx,
             float* __restrict__ ws_avg, float* __restrict__ ws_scal)
{
    __shared__ float sp_lds[KC][PAD];
    __shared__ float xn_lds[RPB][PAD];
    __shared__ float A_lds[RPB];
    __shared__ float red[8];

    const int tid = threadIdx.x;
    const int c   = tid & (KSPLIT - 1);     // K-split lane 0..15
    const int rg  = tid >> 4;               // row-group 0..15
    const int r0l = rg * 2;                 // local row ids
    const int r1l = r0l + 1;
    const int row0 = blockIdx.x * RPB + r0l;
    const int row1 = row0 + 1;
    const int b0 = row0 >> 12, p0 = row0 & 4095;
    const int b1 = row1 >> 12, p1 = row1 & 4095;

    // ---- load 2 rows of x and normalize (fully static indexing) ----
    float xn0[D], xn1[D];
    float ss0 = 0.f, ss1 = 0.f;
#pragma unroll
    for (int j = 0; j < D; ++j) {
        float v0 = x[(b0 * D + j) * 4096 + p0];
        float v1 = x[(b1 * D + j) * 4096 + p1];
        xn0[j] = v0; ss0 += v0 * v0;
        xn1[j] = v1; ss1 += v1 * v1;
    }
    const float inv0 = 1.0f / sqrtf(ss0);
    const float inv1 = 1.0f / sqrtf(ss1);
#pragma unroll
    for (int j = 0; j < D; ++j) { xn0[j] *= inv0; xn1[j] *= inv1; }

    if (c == 0) {
#pragma unroll
        for (int j = 0; j < D; ++j) {
            xn_lds[r0l][j] = xn0[j];
            xn_lds[r1l][j] = xn1[j];
        }
    }

    // ---- pass 1: fixed-shift softmax (shift = 100, since sims <= 1) ----
    // e = exp(100 s - 100); Z = sum e; S = sum (s-1) e; track max+argmax.
    float m0 = -1e30f, Z0 = 0.f, S0 = 0.f;
    float m1 = -1e30f, Z1 = 0.f, S1 = 0.f;
    int i0 = 0, i1 = 0;

    for (int ch = 0; ch < NCHUNK; ++ch) {
        __syncthreads();
        for (int t = tid; t < KC * D; t += 256) {
            int r = t / D;
            int j = t - r * D;
            sp_lds[r][j] = sp[ch * (KC * D) + t];
        }
        __syncthreads();

#pragma unroll
        for (int jj = 0; jj < KPTC; ++jj) {
            const float* sr = &sp_lds[c + jj * KSPLIT][0];
            float4 a0 = *(const float4*)(sr);
            float4 a1 = *(const float4*)(sr + 4);
            float4 a2 = *(const float4*)(sr + 8);
            float4 a3 = *(const float4*)(sr + 12);
            float2 a4 = *(const float2*)(sr + 16);
            float s0 = dot18(a0, a1, a2, a3, a4, xn0);
            float s1 = dot18(a0, a1, a2, a3, a4, xn1);
            const int k = ch * KC + c + jj * KSPLIT;
            if (s0 > m0) { m0 = s0; i0 = k; }
            if (s1 > m1) { m1 = s1; i1 = k; }
            float e0 = exp2f(fmaf(P100, s0, -P100));
            float e1 = exp2f(fmaf(P100, s1, -P100));
            Z0 += e0; S0 = fmaf(s0 - 1.0f, e0, S0);
            Z1 += e1; S1 = fmaf(s1 - 1.0f, e1, S1);
        }
    }

    // ---- merge the 16 K-split lanes (Z,S are plain sums; max+first-idx) ----
#pragma unroll
    for (int off = 1; off < KSPLIT; off <<= 1) {
        Z0 += __shfl_xor(Z0, off);
        S0 += __shfl_xor(S0, off);
        Z1 += __shfl_xor(Z1, off);
        S1 += __shfl_xor(S1, off);
        float mm0 = __shfl_xor(m0, off); int ii0 = __shfl_xor(i0, off);
        float mm1 = __shfl_xor(m1, off); int ii1 = __shfl_xor(i1, off);
        if (mm0 > m0 || (mm0 == m0 && ii0 < i0)) { m0 = mm0; i0 = ii0; }
        if (mm1 > m1 || (mm1 == m1 && ii1 < i1)) { m1 = mm1; i1 = ii1; }
    }

    // entropy = ln Z - 100 * S / Z  (fixed shift cancels)
    const float l2Z0 = log2f(Z0);
    const float l2Z1 = log2f(Z1);
    const float ent0 = l2Z0 * LN2f - 100.f * (S0 / Z0);
    const float ent1 = l2Z1 * LN2f - 100.f * (S1 / Z1);

    if (c == 0) {
        A_lds[r0l] = P100 + l2Z0;     // p = exp2(P100*s - A)
        A_lds[r1l] = P100 + l2Z1;
        out_idx[row0] = (float)i0;
        out_idx[row1] = (float)i1;
    }

    // ---- q gather/write + commitment partial (channel c per lane) ----
    float cpart = 0.f;
    {
        float q0 = sp[i0 * D + c];
        float q1 = sp[i1 * D + c];
        out_q[(b0 * D + c) * 4096 + p0] = q0;
        out_q[(b1 * D + c) * 4096 + p1] = q1;
        float d0 = xn_lds[r0l][c] - q0;
        float d1 = xn_lds[r1l][c] - q1;
        cpart = d0 * d0 + d1 * d1;
        if (c < 2) {
            float q0b = sp[i0 * D + 16 + c];
            float q1b = sp[i1 * D + 16 + c];
            out_q[(b0 * D + 16 + c) * 4096 + p0] = q0b;
            out_q[(b1 * D + 16 + c) * 4096 + p1] = q1b;
            float d0b = xn_lds[r0l][16 + c] - q0b;
            float d1b = xn_lds[r1l][16 + c] - q1b;
            cpart += d0b * d0b + d1b * d1b;
        }
    }

    // ---- block-reduce entropy & commit, one atomic each per block ----
    float v1 = (ent0 + ent1) * (1.0f / 16.0f);   // 16 duplicate lanes per group
    float v2 = cpart;
#pragma unroll
    for (int off = 1; off < 64; off <<= 1) {
        v1 += __shfl_xor(v1, off);
        v2 += __shfl_xor(v2, off);
    }
    const int wid = tid >> 6;
    if ((tid & 63) == 0) { red[wid] = v1; red[wid + 4] = v2; }
    __syncthreads();
    if (tid == 0) {
        atomicAdd(&ws_scal[0], red[0] + red[1] + red[2] + red[3]);
        atomicAdd(&ws_scal[1], red[4] + red[5] + red[6] + red[7]);
    }
    // barrier above also publishes xn_lds / A_lds for pass 2

    // ---- pass 2: avg_probs. Thread owns 4 consecutive k's in registers. ----
#pragma unroll 1
    for (int kb = 0; kb < 4; ++kb) {
        const int k0 = kb * 1024 + tid * 4;
        float skr[4][D];
#pragma unroll
        for (int kk = 0; kk < 4; ++kk)
#pragma unroll
            for (int j = 0; j < D; ++j)
                skr[kk][j] = sp[(k0 + kk) * D + j];

        float acc[4] = {0.f, 0.f, 0.f, 0.f};
#pragma unroll 1
        for (int r = 0; r < RPB; ++r) {
            const float* xr = &xn_lds[r][0];
            float4 b0v = *(const float4*)(xr);
            float4 b1v = *(const float4*)(xr + 4);
            float4 b2v = *(const float4*)(xr + 8);
            float4 b3v = *(const float4*)(xr + 12);
            float2 b4v = *(const float2*)(xr + 16);
            const float negA = -A_lds[r];
#pragma unroll
            for (int kk = 0; kk < 4; ++kk) {
                float dot = dot18(b0v, b1v, b2v, b3v, b4v, skr[kk]);
                acc[kk] += exp2f(fmaf(P100, dot, negA));
            }
        }
#pragma unroll
        for (int kk = 0; kk < 4; ++kk)
            atomicAdd(&ws_avg[k0 + kk], acc[kk]);
    }
}

__global__ void hs_final(const float* __restrict__ ws_avg,
                         const float* __restrict__ ws_scal,
                         float* __restrict__ out)
{
    __shared__ float red[4];
    const int tid = threadIdx.x;
    float local = 0.f;
    for (int k = tid; k < KCB; k += 256) {
        float a = ws_avg[k] * (1.0f / 32768.0f);
        local += a * (log2f(a + 1e-15f) * LN2f);
    }
#pragma unroll
    for (int off = 1; off < 64; off <<= 1) local += __shfl_xor(local, off);
    if ((tid & 63) == 0) red[tid >> 6] = local;
    __syncthreads();
    if (tid == 0) {
        float mean_entro = -(red[0] + red[1] + red[2] + red[3]);
        float entro_mean = ws_scal[0] * (1.0f / 32768.0f);
        float commit     = ws_scal[1] * (1.0f / (32768.0f * 18.0f));
        out[SCL_OFF + 0] = entro_mean;
        out[SCL_OFF + 1] = mean_entro;
        out[SCL_OFF + 2] = entro_mean - mean_entro;
        out[SCL_OFF + 3] = commit;
    }
}

extern "C" void kernel_launch(void* const* d_in, const int* in_sizes, int n_in,
                              void* d_out, int out_size, void* d_ws, size_t ws_size,
                              hipStream_t stream)
{
    const float* x  = (const float*)d_in[0];
    const float* sp = (const float*)d_in[1];
    float* out = (float*)d_out;
    float* ws  = (float*)d_ws;

    // ws layout: [0..4095] avg_probs sums, [4096] entropy sum, [4097] commit sum
    hipMemsetAsync(ws, 0, (KCB + 2) * sizeof(float), stream);

    hs_main<<<NROW / RPB, 256, 0, stream>>>(x, sp,
                                            out + Q_OFF, out + IDX_OFF,
                                            ws, ws + KCB);
    hs_final<<<1, 256, 0, stream>>>(ws, ws + KCB, out);
}

// Round 4
// 262.302 us; speedup vs baseline: 1.2811x; 1.2811x over previous
//
#include <hip/hip_runtime.h>
#include <hip/hip_bf16.h>
#include <math.h>

// Problem constants
#define D      18
#define KCB    4096      // codebook entries
#define NROW   32768     // 8 * 64 * 64
#define KSPLIT 16        // lanes per row-group (split over K)
#define RPB    32        // rows per block
#define KC     128       // K chunk staged in LDS
#define KPTC   8         // k's per thread per chunk (KC/KSPLIT)
#define NCHUNK 32        // KCB / KC
#define PAD    20        // padded row stride in LDS floats (80B)

#define P100    144.26950408889634f   // 100 * log2(e)
#define NEGP100 (-144.26950408889634f)
#define LN2f    0.6931471805599453f

#define Q_OFF   0
#define IDX_OFF 589824               // 8*18*64*64
#define SCL_OFF 622592               // + 32768

// 18-term fma chain seeded with SEED; A-side is float4 a0..a3 + float2 a4.
#define CHAIN18(T, XS, SEED)                                            \
    float T = fmaf((XS)[0], a0.x, (SEED));                              \
    T = fmaf((XS)[1], a0.y, T);  T = fmaf((XS)[2], a0.z, T);            \
    T = fmaf((XS)[3], a0.w, T);  T = fmaf((XS)[4], a1.x, T);            \
    T = fmaf((XS)[5], a1.y, T);  T = fmaf((XS)[6], a1.z, T);            \
    T = fmaf((XS)[7], a1.w, T);  T = fmaf((XS)[8], a2.x, T);            \
    T = fmaf((XS)[9], a2.y, T);  T = fmaf((XS)[10], a2.z, T);           \
    T = fmaf((XS)[11], a2.w, T); T = fmaf((XS)[12], a3.x, T);           \
    T = fmaf((XS)[13], a3.y, T); T = fmaf((XS)[14], a3.z, T);           \
    T = fmaf((XS)[15], a3.w, T); T = fmaf((XS)[16], a4.x, T);           \
    T = fmaf((XS)[17], a4.y, T);

__global__ void hs_main(const float* __restrict__ x, const float* __restrict__ sp,
                        float* __restrict__ out_q, float* __restrict__ out_idx,
                        float* __restrict__ ws_avg, float* __restrict__ ws_scal)
{
    __shared__ float sp_lds[KC][PAD];
    __shared__ float xn_lds[RPB][PAD];   // raw normalized rows (commit/q)
    __shared__ float xs_lds[RPB][PAD];   // P100-scaled rows (pass 2)
    __shared__ float An_lds[RPB];        // -(P100 + log2 Z)  (pass-2 seed)
    __shared__ float red[8];

    const int tid = threadIdx.x;
    const int c   = tid & (KSPLIT - 1);     // K-split lane 0..15
    const int rg  = tid >> 4;               // row-group 0..15
    const int r0l = rg * 2;
    const int r1l = r0l + 1;
    const int row0 = blockIdx.x * RPB + r0l;
    const int row1 = row0 + 1;
    const int b0 = row0 >> 12, p0 = row0 & 4095;
    const int b1 = row1 >> 12, p1 = row1 & 4095;

    // ---- load 2 rows of x, normalize, and pre-scale by P100 ----
    float xs0[D], xs1[D];
    float ss0 = 0.f, ss1 = 0.f;
#pragma unroll
    for (int j = 0; j < D; ++j) {
        float v0 = x[(b0 * D + j) * 4096 + p0];
        float v1 = x[(b1 * D + j) * 4096 + p1];
        xs0[j] = v0; ss0 += v0 * v0;
        xs1[j] = v1; ss1 += v1 * v1;
    }
    const float inv0 = 1.0f / sqrtf(ss0);
    const float inv1 = 1.0f / sqrtf(ss1);
    if (c == 0) {
#pragma unroll
        for (int j = 0; j < D; ++j) {
            xn_lds[r0l][j] = xs0[j] * inv0;
            xn_lds[r1l][j] = xs1[j] * inv1;
        }
    }
    const float s0f = inv0 * P100;
    const float s1f = inv1 * P100;
#pragma unroll
    for (int j = 0; j < D; ++j) { xs0[j] *= s0f; xs1[j] *= s1f; }
    if (c == 0) {
#pragma unroll
        for (int j = 0; j < D; ++j) {
            xs_lds[r0l][j] = xs0[j];
            xs_lds[r1l][j] = xs1[j];
        }
    }

    // ---- pass 1: t = P100*s - P100 per (row,k); Z=sum e, S=sum t*e ----
    float Z0 = 0.f, S0 = 0.f, m0 = -1e30f;
    float Z1 = 0.f, S1 = 0.f, m1 = -1e30f;
    int i0 = 0, i1 = 0;

    for (int ch = 0; ch < NCHUNK; ++ch) {
        __syncthreads();
        for (int t = tid; t < KC * D; t += 256) {
            int r = t / D;
            int j = t - r * D;
            sp_lds[r][j] = sp[ch * (KC * D) + t];
        }
        __syncthreads();

#pragma unroll
        for (int jj = 0; jj < KPTC; ++jj) {
            const float* sr = &sp_lds[jj * KSPLIT + c][0];
            float4 a0 = *(const float4*)(sr);
            float4 a1 = *(const float4*)(sr + 4);
            float4 a2 = *(const float4*)(sr + 8);
            float4 a3 = *(const float4*)(sr + 12);
            float2 a4 = *(const float2*)(sr + 16);
            CHAIN18(t0, xs0, NEGP100);
            CHAIN18(t1, xs1, NEGP100);
            const int k = ch * KC + jj * KSPLIT + c;
            if (t0 > m0) { m0 = t0; i0 = k; }
            if (t1 > m1) { m1 = t1; i1 = k; }
            float e0 = __builtin_amdgcn_exp2f(t0);
            float e1 = __builtin_amdgcn_exp2f(t1);
            Z0 += e0; S0 = fmaf(t0, e0, S0);
            Z1 += e1; S1 = fmaf(t1, e1, S1);
        }
    }

    // ---- merge the 16 K-split lanes ----
#pragma unroll
    for (int off = 1; off < KSPLIT; off <<= 1) {
        Z0 += __shfl_xor(Z0, off);
        S0 += __shfl_xor(S0, off);
        Z1 += __shfl_xor(Z1, off);
        S1 += __shfl_xor(S1, off);
        float mm0 = __shfl_xor(m0, off); int ii0 = __shfl_xor(i0, off);
        float mm1 = __shfl_xor(m1, off); int ii1 = __shfl_xor(i1, off);
        if (mm0 > m0 || (mm0 == m0 && ii0 < i0)) { m0 = mm0; i0 = ii0; }
        if (mm1 > m1 || (mm1 == m1 && ii1 < i1)) { m1 = mm1; i1 = ii1; }
    }

    // entropy = ln2 * (log2 Z - S/Z)   [S accumulates t*e, t = P100*(s-1)]
    const float l2Z0 = log2f(Z0);
    const float l2Z1 = log2f(Z1);
    const float ent0 = LN2f * (l2Z0 - S0 / Z0);
    const float ent1 = LN2f * (l2Z1 - S1 / Z1);

    if (c == 0) {
        An_lds[r0l] = -(P100 + l2Z0);   // pass-2 seed: exp2(P100*s + An)
        An_lds[r1l] = -(P100 + l2Z1);
        out_idx[row0] = (float)i0;
        out_idx[row1] = (float)i1;
    }

    // ---- q gather/write + commitment partial (channel c per lane) ----
    float cpart = 0.f;
    {
        float q0 = sp[i0 * D + c];
        float q1 = sp[i1 * D + c];
        out_q[(b0 * D + c) * 4096 + p0] = q0;
        out_q[(b1 * D + c) * 4096 + p1] = q1;
        float d0 = xn_lds[r0l][c] - q0;
        float d1 = xn_lds[r1l][c] - q1;
        cpart = d0 * d0 + d1 * d1;
        if (c < 2) {
            float q0b = sp[i0 * D + 16 + c];
            float q1b = sp[i1 * D + 16 + c];
            out_q[(b0 * D + 16 + c) * 4096 + p0] = q0b;
            out_q[(b1 * D + 16 + c) * 4096 + p1] = q1b;
            float d0b = xn_lds[r0l][16 + c] - q0b;
            float d1b = xn_lds[r1l][16 + c] - q1b;
            cpart += d0b * d0b + d1b * d1b;
        }
    }

    // ---- block-reduce entropy & commit, one atomic each per block ----
    float v1 = (ent0 + ent1) * (1.0f / 16.0f);   // 16 duplicate lanes per group
    float v2 = cpart;
#pragma unroll
    for (int off = 1; off < 64; off <<= 1) {
        v1 += __shfl_xor(v1, off);
        v2 += __shfl_xor(v2, off);
    }
    const int wid = tid >> 6;
    if ((tid & 63) == 0) { red[wid] = v1; red[wid + 4] = v2; }
    __syncthreads();     // also publishes xn/xs/An for pass 2
    if (tid == 0) {
        atomicAdd(&ws_scal[0], red[0] + red[1] + red[2] + red[3]);
        atomicAdd(&ws_scal[1], red[4] + red[5] + red[6] + red[7]);
    }

    // ---- pass 2: avg_probs; thread owns 4 consecutive k's in registers ----
#pragma unroll 1
    for (int kb = 0; kb < 4; ++kb) {
        const int k0 = kb * 1024 + tid * 4;
        float2 sk2[4][9];
#pragma unroll
        for (int kk = 0; kk < 4; ++kk) {
            const float2* sp2 = (const float2*)(sp + (k0 + kk) * D);
#pragma unroll
            for (int j = 0; j < 9; ++j) sk2[kk][j] = sp2[j];
        }

        float acc[4] = {0.f, 0.f, 0.f, 0.f};
#pragma unroll 1
        for (int r = 0; r < RPB; ++r) {
            const float2* xr2 = (const float2*)&xs_lds[r][0];
            float2 xv[9];
#pragma unroll
            for (int j = 0; j < 9; ++j) xv[j] = xr2[j];
            const float seed = An_lds[r];
#pragma unroll
            for (int kk = 0; kk < 4; ++kk) {
                float d = fmaf(sk2[kk][0].x, xv[0].x, seed);
                d = fmaf(sk2[kk][0].y, xv[0].y, d);
#pragma unroll
                for (int j = 1; j < 9; ++j) {
                    d = fmaf(sk2[kk][j].x, xv[j].x, d);
                    d = fmaf(sk2[kk][j].y, xv[j].y, d);
                }
                acc[kk] += __builtin_amdgcn_exp2f(d);
            }
        }
#pragma unroll
        for (int kk = 0; kk < 4; ++kk)
            atomicAdd(&ws_avg[k0 + kk], acc[kk]);
    }
}

__global__ void hs_final(const float* __restrict__ ws_avg,
                         const float* __restrict__ ws_scal,
                         float* __restrict__ out)
{
    __shared__ float red[4];
    const int tid = threadIdx.x;
    float local = 0.f;
    for (int k = tid; k < KCB; k += 256) {
        float a = ws_avg[k] * (1.0f / 32768.0f);
        local += a * (log2f(a + 1e-15f) * LN2f);
    }
#pragma unroll
    for (int off = 1; off < 64; off <<= 1) local += __shfl_xor(local, off);
    if ((tid & 63) == 0) red[tid >> 6] = local;
    __syncthreads();
    if (tid == 0) {
        float mean_entro = -(red[0] + red[1] + red[2] + red[3]);
        float entro_mean = ws_scal[0] * (1.0f / 32768.0f);
        float commit     = ws_scal[1] * (1.0f / (32768.0f * 18.0f));
        out[SCL_OFF + 0] = entro_mean;
        out[SCL_OFF + 1] = mean_entro;
        out[SCL_OFF + 2] = entro_mean - mean_entro;
        out[SCL_OFF + 3] = commit;
    }
}

extern "C" void kernel_launch(void* const* d_in, const int* in_sizes, int n_in,
                              void* d_out, int out_size, void* d_ws, size_t ws_size,
                              hipStream_t stream)
{
    const float* x  = (const float*)d_in[0];
    const float* sp = (const float*)d_in[1];
    float* out = (float*)d_out;
    float* ws  = (float*)d_ws;

    // ws layout: [0..4095] avg_probs sums, [4096] entropy sum, [4097] commit sum
    hipMemsetAsync(ws, 0, (KCB + 2) * sizeof(float), stream);

    hs_main<<<NROW / RPB, 256, 0, stream>>>(x, sp,
                                            out + Q_OFF, out + IDX_OFF,
                                            ws, ws + KCB);
    hs_final<<<1, 256, 0, stream>>>(ws, ws + KCB, out);
}

// Round 5
// 259.974 us; speedup vs baseline: 1.2926x; 1.0090x over previous
//
#include <hip/hip_runtime.h>
#include <hip/hip_bf16.h>
#include <math.h>

// Problem constants
#define D      18
#define KCB    4096      // codebook entries
#define NROW   32768     // 8 * 64 * 64
#define KSPLIT 16        // lanes per row-group (split over K)
#define RPB    32        // rows per block
#define KC     128       // k's per outer iteration
#define KPTC   8         // k's per thread per outer iteration (KC/KSPLIT)
#define NCHUNK 32        // KCB / KC
#define PAD    20        // padded row stride in LDS floats (80B)
#define NBLK   (NROW / RPB)   // 1024 blocks

#define P100    144.26950408889634f   // 100 * log2(e)
#define NEGP100 (-144.26950408889634f)
#define LN2f    0.6931471805599453f

#define Q_OFF   0
#define IDX_OFF 589824               // 8*18*64*64
#define SCL_OFF 622592               // + 32768

// ws layout (floats): [0] entropy-sum, [1] commit-sum, [2..2+KCB) k-vector sums,
// then (optional, if ws_size permits) NBLK*KCB per-block partials at WS_HDR.
#define WS_HDR  8192

// 18-term fma chain over 9 float2 regs a0..a8, seeded with SEED.
// Summation order identical to the verified round-4 kernel (j = 0..17).
#define CHAIN18F2(T, XS, SEED)                                          \
    float T = fmaf((XS)[0], a0.x, (SEED));                              \
    T = fmaf((XS)[1],  a0.y, T); T = fmaf((XS)[2],  a1.x, T);           \
    T = fmaf((XS)[3],  a1.y, T); T = fmaf((XS)[4],  a2.x, T);           \
    T = fmaf((XS)[5],  a2.y, T); T = fmaf((XS)[6],  a3.x, T);           \
    T = fmaf((XS)[7],  a3.y, T); T = fmaf((XS)[8],  a4.x, T);           \
    T = fmaf((XS)[9],  a4.y, T); T = fmaf((XS)[10], a5.x, T);           \
    T = fmaf((XS)[11], a5.y, T); T = fmaf((XS)[12], a6.x, T);           \
    T = fmaf((XS)[13], a6.y, T); T = fmaf((XS)[14], a7.x, T);           \
    T = fmaf((XS)[15], a7.y, T); T = fmaf((XS)[16], a8.x, T);           \
    T = fmaf((XS)[17], a8.y, T);

__global__ __launch_bounds__(256, 4)
void hs_main(const float* __restrict__ x, const float* __restrict__ sp,
             float* __restrict__ out_q, float* __restrict__ out_idx,
             float* __restrict__ ws_scal, float* __restrict__ ws_kvec,
             float* __restrict__ ws_part)
{
    __shared__ float xn_lds[RPB][PAD];   // raw normalized rows (commit/q)
    __shared__ float xs_lds[RPB][PAD];   // P100-scaled rows (pass 2)
    __shared__ float An_lds[RPB];        // -(P100 + log2 Z)  (pass-2 seed)
    __shared__ float red[8];

    const int tid = threadIdx.x;
    const int c   = tid & (KSPLIT - 1);     // K-split lane 0..15
    const int rg  = tid >> 4;               // row-group 0..15
    const int r0l = rg * 2;
    const int r1l = r0l + 1;
    const int row0 = blockIdx.x * RPB + r0l;
    const int row1 = row0 + 1;
    const int b0 = row0 >> 12, p0 = row0 & 4095;
    const int b1 = row1 >> 12, p1 = row1 & 4095;

    // ---- load 2 rows of x, normalize, pre-scale by P100 ----
    float xs0[D], xs1[D];
    float ss0 = 0.f, ss1 = 0.f;
#pragma unroll
    for (int j = 0; j < D; ++j) {
        float v0 = x[(b0 * D + j) * 4096 + p0];
        float v1 = x[(b1 * D + j) * 4096 + p1];
        xs0[j] = v0; ss0 += v0 * v0;
        xs1[j] = v1; ss1 += v1 * v1;
    }
    const float inv0 = 1.0f / sqrtf(ss0);
    const float inv1 = 1.0f / sqrtf(ss1);
    if (c == 0) {
#pragma unroll
        for (int j = 0; j < D; ++j) {
            xn_lds[r0l][j] = xs0[j] * inv0;
            xn_lds[r1l][j] = xs1[j] * inv1;
        }
    }
    const float s0f = inv0 * P100;
    const float s1f = inv1 * P100;
#pragma unroll
    for (int j = 0; j < D; ++j) { xs0[j] *= s0f; xs1[j] *= s1f; }
    if (c == 0) {
#pragma unroll
        for (int j = 0; j < D; ++j) {
            xs_lds[r0l][j] = xs0[j];
            xs_lds[r1l][j] = xs1[j];
        }
    }

    // ---- pass 1: direct-global codebook reads (sp is L2-resident, 288KB) ----
    // t = P100*s - P100; Z = sum e; S = sum t*e; track max+argmax on t.
    float Z0 = 0.f, S0 = 0.f, m0 = -1e30f;
    float Z1 = 0.f, S1 = 0.f, m1 = -1e30f;
    int i0 = 0, i1 = 0;

    const float2* kp = (const float2*)(sp + c * D);   // 72B row stride -> 8B aligned
#pragma unroll 1
    for (int ch = 0; ch < NCHUNK; ++ch) {
#pragma unroll
        for (int jj = 0; jj < KPTC; ++jj) {
            const float2* sr = kp + (ch * KC + jj * KSPLIT) * (D / 2);
            float2 a0 = sr[0], a1 = sr[1], a2 = sr[2];
            float2 a3 = sr[3], a4 = sr[4], a5 = sr[5];
            float2 a6 = sr[6], a7 = sr[7], a8 = sr[8];
            CHAIN18F2(t0, xs0, NEGP100);
            CHAIN18F2(t1, xs1, NEGP100);
            const int k = ch * KC + jj * KSPLIT + c;
            if (t0 > m0) { m0 = t0; i0 = k; }
            if (t1 > m1) { m1 = t1; i1 = k; }
            float e0 = __builtin_amdgcn_exp2f(t0);
            float e1 = __builtin_amdgcn_exp2f(t1);
            Z0 += e0; S0 = fmaf(t0, e0, S0);
            Z1 += e1; S1 = fmaf(t1, e1, S1);
        }
    }

    // ---- merge the 16 K-split lanes ----
#pragma unroll
    for (int off = 1; off < KSPLIT; off <<= 1) {
        Z0 += __shfl_xor(Z0, off);
        S0 += __shfl_xor(S0, off);
        Z1 += __shfl_xor(Z1, off);
        S1 += __shfl_xor(S1, off);
        float mm0 = __shfl_xor(m0, off); int ii0 = __shfl_xor(i0, off);
        float mm1 = __shfl_xor(m1, off); int ii1 = __shfl_xor(i1, off);
        if (mm0 > m0 || (mm0 == m0 && ii0 < i0)) { m0 = mm0; i0 = ii0; }
        if (mm1 > m1 || (mm1 == m1 && ii1 < i1)) { m1 = mm1; i1 = ii1; }
    }

    // entropy = ln2 * (log2 Z - S/Z)
    const float l2Z0 = log2f(Z0);
    const float l2Z1 = log2f(Z1);
    const float ent0 = LN2f * (l2Z0 - S0 / Z0);
    const float ent1 = LN2f * (l2Z1 - S1 / Z1);

    if (c == 0) {
        An_lds[r0l] = -(P100 + l2Z0);   // pass-2 seed: exp2(P100*s + An)
        An_lds[r1l] = -(P100 + l2Z1);
        out_idx[row0] = (float)i0;
        out_idx[row1] = (float)i1;
    }

    // ---- q gather/write + commitment partial (channel c per lane) ----
    float cpart = 0.f;
    {
        float q0 = sp[i0 * D + c];
        float q1 = sp[i1 * D + c];
        out_q[(b0 * D + c) * 4096 + p0] = q0;
        out_q[(b1 * D + c) * 4096 + p1] = q1;
        float d0 = xn_lds[r0l][c] - q0;
        float d1 = xn_lds[r1l][c] - q1;
        cpart = d0 * d0 + d1 * d1;
        if (c < 2) {
            float q0b = sp[i0 * D + 16 + c];
            float q1b = sp[i1 * D + 16 + c];
            out_q[(b0 * D + 16 + c) * 4096 + p0] = q0b;
            out_q[(b1 * D + 16 + c) * 4096 + p1] = q1b;
            float d0b = xn_lds[r0l][16 + c] - q0b;
            float d1b = xn_lds[r1l][16 + c] - q1b;
            cpart += d0b * d0b + d1b * d1b;
        }
    }

    // ---- block-reduce entropy & commit, one atomic each per block ----
    float v1 = (ent0 + ent1) * (1.0f / 16.0f);   // 16 duplicate lanes per group
    float v2 = cpart;
#pragma unroll
    for (int off = 1; off < 64; off <<= 1) {
        v1 += __shfl_xor(v1, off);
        v2 += __shfl_xor(v2, off);
    }
    const int wid = tid >> 6;
    if ((tid & 63) == 0) { red[wid] = v1; red[wid + 4] = v2; }
    __syncthreads();     // also publishes xn/xs/An for pass 2
    if (tid == 0) {
        atomicAdd(&ws_scal[0], red[0] + red[1] + red[2] + red[3]);
        atomicAdd(&ws_scal[1], red[4] + red[5] + red[6] + red[7]);
    }

    // ---- pass 2: avg_probs; thread owns 4 consecutive k's in registers ----
    float* part_dst = ws_part ? (ws_part + blockIdx.x * KCB) : nullptr;
#pragma unroll 1
    for (int kb = 0; kb < 4; ++kb) {
        const int k0 = kb * 1024 + tid * 4;
        float2 sk2[4][9];
#pragma unroll
        for (int kk = 0; kk < 4; ++kk) {
            const float2* sp2 = (const float2*)(sp + (k0 + kk) * D);
#pragma unroll
            for (int j = 0; j < 9; ++j) sk2[kk][j] = sp2[j];
        }

        float acc[4] = {0.f, 0.f, 0.f, 0.f};
#pragma unroll 2
        for (int r = 0; r < RPB; ++r) {
            const float2* xr2 = (const float2*)&xs_lds[r][0];
            float2 xv[9];
#pragma unroll
            for (int j = 0; j < 9; ++j) xv[j] = xr2[j];
            const float seed = An_lds[r];
#pragma unroll
            for (int kk = 0; kk < 4; ++kk) {
                float d = fmaf(sk2[kk][0].x, xv[0].x, seed);
                d = fmaf(sk2[kk][0].y, xv[0].y, d);
#pragma unroll
                for (int j = 1; j < 9; ++j) {
                    d = fmaf(sk2[kk][j].x, xv[j].x, d);
                    d = fmaf(sk2[kk][j].y, xv[j].y, d);
                }
                acc[kk] += __builtin_amdgcn_exp2f(d);
            }
        }
        if (part_dst) {
            float4 st = make_float4(acc[0], acc[1], acc[2], acc[3]);
            *(float4*)(part_dst + k0) = st;          // streaming, coalesced
        } else {
#pragma unroll
            for (int kk = 0; kk < 4; ++kk)
                atomicAdd(&ws_kvec[k0 + kk], acc[kk]);
        }
    }
}

// Reduce NBLK x KCB partials into ws_kvec. Grid 256: block = (sb, kb),
// sb = 16 slabs of 64 blocks, kb = 16 slabs of 256 k's. 16 atomics per k.
__global__ void hs_reduce(const float* __restrict__ part, float* __restrict__ kvec)
{
    const int kb = blockIdx.x & 15;
    const int sb = blockIdx.x >> 4;
    const int k  = kb * 256 + threadIdx.x;
    const float* p = part + (size_t)sb * 64 * KCB + k;
    float s = 0.f;
#pragma unroll 8
    for (int b = 0; b < 64; ++b) s += p[b * KCB];
    atomicAdd(&kvec[k], s);
}

__global__ void hs_final(const float* __restrict__ ws_kvec,
                         const float* __restrict__ ws_scal,
                         float* __restrict__ out)
{
    __shared__ float red[4];
    const int tid = threadIdx.x;
    float local = 0.f;
    for (int k = tid; k < KCB; k += 256) {
        float a = ws_kvec[k] * (1.0f / 32768.0f);
        local += a * (log2f(a + 1e-15f) * LN2f);
    }
#pragma unroll
    for (int off = 1; off < 64; off <<= 1) local += __shfl_xor(local, off);
    if ((tid & 63) == 0) red[tid >> 6] = local;
    __syncthreads();
    if (tid == 0) {
        float mean_entro = -(red[0] + red[1] + red[2] + red[3]);
        float entro_mean = ws_scal[0] * (1.0f / 32768.0f);
        float commit     = ws_scal[1] * (1.0f / (32768.0f * 18.0f));
        out[SCL_OFF + 0] = entro_mean;
        out[SCL_OFF + 1] = mean_entro;
        out[SCL_OFF + 2] = entro_mean - mean_entro;
        out[SCL_OFF + 3] = commit;
    }
}

extern "C" void kernel_launch(void* const* d_in, const int* in_sizes, int n_in,
                              void* d_out, int out_size, void* d_ws, size_t ws_size,
                              hipStream_t stream)
{
    const float* x  = (const float*)d_in[0];
    const float* sp = (const float*)d_in[1];
    float* out = (float*)d_out;
    float* ws  = (float*)d_ws;

    const bool partials =
        ws_size >= (size_t)(WS_HDR + (size_t)NBLK * KCB) * sizeof(float);

    hipMemsetAsync(ws, 0, WS_HDR * sizeof(float), stream);

    hs_main<<<NBLK, 256, 0, stream>>>(x, sp, out + Q_OFF, out + IDX_OFF,
                                      ws, ws + 2,
                                      partials ? ws + WS_HDR : nullptr);
    if (partials)
        hs_reduce<<<256, 256, 0, stream>>>(ws + WS_HDR, ws + 2);
    hs_final<<<1, 256, 0, stream>>>(ws + 2, ws, out);
}

// Round 6
// 178.953 us; speedup vs baseline: 1.8778x; 1.4528x over previous
//
#include <hip/hip_runtime.h>
#include <hip/hip_bf16.h>
#include <math.h>

// Problem constants
#define D       18
#define KCB     4096       // codebook entries
#define NROW    32768      // 8 * 64 * 64
#define RPB     64         // rows per block (= lanes per wave)
#define NWAVE   8          // waves per block; each owns a 512-k slice
#define KSLICE  512        // k's per wave slice
#define NBLK    (NROW / RPB)   // 512 blocks
#define PAD     20         // padded row stride in LDS floats (80B)

#define P100     144.26950408889634f   // 100 * log2(e)
#define NEGP100  (-144.26950408889634f)
#define LN2f     0.6931471805599453f
#define INVP100  0.006931471805599453f // 1/P100 = ln2/100

#define Q_OFF   0
#define IDX_OFF 589824               // 8*18*64*64
#define SCL_OFF 622592               // + 32768

// ws layout (floats): [0] entropy-sum, [1] commit-sum, [2..2+KCB) k sums,
// then (if ws_size permits) NBLK*KCB per-block partials at WS_HDR.
#define WS_HDR  8192

__global__ __launch_bounds__(512, 4)
void hs_main(const float* __restrict__ x, const float* __restrict__ sp,
             float* __restrict__ out_q, float* __restrict__ out_idx,
             float* __restrict__ ws_scal, float* __restrict__ ws_part,
             float* __restrict__ ws_kvec)
{
    __shared__ float xs_lds[RPB][PAD];    // P100-scaled normalized rows
    __shared__ float An_lds[RPB];         // -(P100 + log2 Z)
    __shared__ float pm[NWAVE][RPB];      // per-slice max
    __shared__ float pz[NWAVE][RPB];      // per-slice Z
    __shared__ float ps[NWAVE][RPB];      // per-slice S
    __shared__ int   pi[NWAVE][RPB];      // per-slice argmax

    const int tid = threadIdx.x;
    const int l   = tid & 63;                               // lane = row
    const int wu  = __builtin_amdgcn_readfirstlane(tid >> 6);  // wave id
    const int row = blockIdx.x * RPB + l;
    const int b   = row >> 12;
    const int p   = row & 4095;

    // ---- every wave loads & normalizes its lanes' row (redundant, L2-hot) ----
    float xs[D];
    float ss = 0.f;
#pragma unroll
    for (int j = 0; j < D; ++j) {
        float v = x[(b * D + j) * 4096 + p];
        xs[j] = v;
        ss += v * v;
    }
    const float sf = (1.0f / sqrtf(ss)) * P100;
#pragma unroll
    for (int j = 0; j < D; ++j) xs[j] *= sf;
    if (wu == 0) {
#pragma unroll
        for (int j = 0; j < D; ++j) xs_lds[l][j] = xs[j];
    }

    // ---- pass 1: wave-uniform codebook sweep over this wave's k-slice ----
    // kr is identical across lanes -> scalar (s_load) / broadcast path.
    const int kbeg = wu * KSLICE;
    float Z = 0.f, S = 0.f, m = -1e30f;
    int idx = kbeg;

#pragma unroll 2
    for (int kk = 0; kk < KSLICE; kk += 2) {
        const float4* k4 = (const float4*)(sp + (kbeg + kk) * D); // 144B pair, 16B-aligned
        float4 q0 = k4[0], q1 = k4[1], q2 = k4[2], q3 = k4[3], q4 = k4[4];
        float4 q5 = k4[5], q6 = k4[6], q7 = k4[7], q8 = k4[8];

        float ta = fmaf(xs[0], q0.x, NEGP100);
        ta = fmaf(xs[1],  q0.y, ta); ta = fmaf(xs[2],  q0.z, ta);
        ta = fmaf(xs[3],  q0.w, ta); ta = fmaf(xs[4],  q1.x, ta);
        ta = fmaf(xs[5],  q1.y, ta); ta = fmaf(xs[6],  q1.z, ta);
        ta = fmaf(xs[7],  q1.w, ta); ta = fmaf(xs[8],  q2.x, ta);
        ta = fmaf(xs[9],  q2.y, ta); ta = fmaf(xs[10], q2.z, ta);
        ta = fmaf(xs[11], q2.w, ta); ta = fmaf(xs[12], q3.x, ta);
        ta = fmaf(xs[13], q3.y, ta); ta = fmaf(xs[14], q3.z, ta);
        ta = fmaf(xs[15], q3.w, ta); ta = fmaf(xs[16], q4.x, ta);
        ta = fmaf(xs[17], q4.y, ta);

        float tb = fmaf(xs[0], q4.z, NEGP100);
        tb = fmaf(xs[1],  q4.w, tb); tb = fmaf(xs[2],  q5.x, tb);
        tb = fmaf(xs[3],  q5.y, tb); tb = fmaf(xs[4],  q5.z, tb);
        tb = fmaf(xs[5],  q5.w, tb); tb = fmaf(xs[6],  q6.x, tb);
        tb = fmaf(xs[7],  q6.y, tb); tb = fmaf(xs[8],  q6.z, tb);
        tb = fmaf(xs[9],  q6.w, tb); tb = fmaf(xs[10], q7.x, tb);
        tb = fmaf(xs[11], q7.y, tb); tb = fmaf(xs[12], q7.z, tb);
        tb = fmaf(xs[13], q7.w, tb); tb = fmaf(xs[14], q8.x, tb);
        tb = fmaf(xs[15], q8.y, tb); tb = fmaf(xs[16], q8.z, tb);
        tb = fmaf(xs[17], q8.w, tb);

        if (ta > m) { m = ta; idx = kbeg + kk; }
        if (tb > m) { m = tb; idx = kbeg + kk + 1; }
        float ea = __builtin_amdgcn_exp2f(ta);
        float eb = __builtin_amdgcn_exp2f(tb);
        Z += ea; S = fmaf(ta, ea, S);
        Z += eb; S = fmaf(tb, eb, S);
    }

    pm[wu][l] = m; pz[wu][l] = Z; ps[wu][l] = S; pi[wu][l] = idx;
    __syncthreads();

    // ---- wave 0: merge 8 slices per row, entropy, q/idx/commit epilogue ----
    if (wu == 0) {
        float mt = pm[0][l], Zt = pz[0][l], St = ps[0][l];
        int   it = pi[0][l];
#pragma unroll
        for (int s = 1; s < NWAVE; ++s) {
            float ms = pm[s][l];
            if (ms > mt) { mt = ms; it = pi[s][l]; }   // ascending slices: first max
            Zt += pz[s][l];
            St += ps[s][l];
        }
        const float l2Z = log2f(Zt);
        const float ent = LN2f * (l2Z - St / Zt);
        An_lds[l] = -(P100 + l2Z);
        out_idx[row] = (float)it;

        // gather chosen codeword once; write q; accumulate commit
        float2 g[9];
        const float2* gr = (const float2*)(sp + it * D);
#pragma unroll
        for (int j = 0; j < 9; ++j) g[j] = gr[j];
        float cp = 0.f;
#pragma unroll
        for (int j = 0; j < 9; ++j) {
            float qx = g[j].x, qy = g[j].y;
            float dx = fmaf(xs[2 * j],     INVP100, -qx);
            float dy = fmaf(xs[2 * j + 1], INVP100, -qy);
            cp = fmaf(dx, dx, cp);
            cp = fmaf(dy, dy, cp);
            out_q[(b * D + 2 * j)     * 4096 + p] = qx;
            out_q[(b * D + 2 * j + 1) * 4096 + p] = qy;
        }

        // wave-reduce entropy & commit over the 64 rows, one atomic each
        float v1 = ent, v2 = cp;
#pragma unroll
        for (int off = 1; off < 64; off <<= 1) {
            v1 += __shfl_xor(v1, off);
            v2 += __shfl_xor(v2, off);
        }
        if (l == 0) {
            atomicAdd(&ws_scal[0], v1);
            atomicAdd(&ws_scal[1], v2);
        }
    }
    __syncthreads();   // publish An_lds (xs_lds already visible)

    // ---- pass 2: avg_probs; thread owns 4 consecutive k's, 2 groups ----
    float* part_dst = ws_part ? (ws_part + (size_t)blockIdx.x * KCB) : nullptr;
#pragma unroll 1
    for (int kb = 0; kb < 2; ++kb) {
        const int k0 = kb * 2048 + tid * 4;
        float2 sk2[4][9];
#pragma unroll
        for (int kkk = 0; kkk < 4; ++kkk) {
            const float2* sp2 = (const float2*)(sp + (k0 + kkk) * D);
#pragma unroll
            for (int j = 0; j < 9; ++j) sk2[kkk][j] = sp2[j];
        }

        float acc[4] = {0.f, 0.f, 0.f, 0.f};
#pragma unroll 2
        for (int r = 0; r < RPB; ++r) {
            const float4* xr4 = (const float4*)&xs_lds[r][0];   // 80B stride, 16B-aligned
            float4 xv0 = xr4[0], xv1 = xr4[1], xv2 = xr4[2], xv3 = xr4[3];
            float2 xv4 = *(const float2*)(&xs_lds[r][16]);
            const float seed = An_lds[r];
#pragma unroll
            for (int kkk = 0; kkk < 4; ++kkk) {
                float d = fmaf(sk2[kkk][0].x, xv0.x, seed);
                d = fmaf(sk2[kkk][0].y, xv0.y, d);
                d = fmaf(sk2[kkk][1].x, xv0.z, d);
                d = fmaf(sk2[kkk][1].y, xv0.w, d);
                d = fmaf(sk2[kkk][2].x, xv1.x, d);
                d = fmaf(sk2[kkk][2].y, xv1.y, d);
                d = fmaf(sk2[kkk][3].x, xv1.z, d);
                d = fmaf(sk2[kkk][3].y, xv1.w, d);
                d = fmaf(sk2[kkk][4].x, xv2.x, d);
                d = fmaf(sk2[kkk][4].y, xv2.y, d);
                d = fmaf(sk2[kkk][5].x, xv2.z, d);
                d = fmaf(sk2[kkk][5].y, xv2.w, d);
                d = fmaf(sk2[kkk][6].x, xv3.x, d);
                d = fmaf(sk2[kkk][6].y, xv3.y, d);
                d = fmaf(sk2[kkk][7].x, xv3.z, d);
                d = fmaf(sk2[kkk][7].y, xv3.w, d);
                d = fmaf(sk2[kkk][8].x, xv4.x, d);
                d = fmaf(sk2[kkk][8].y, xv4.y, d);
                acc[kkk] += __builtin_amdgcn_exp2f(d);
            }
        }
        if (part_dst) {
            float4 st = make_float4(acc[0], acc[1], acc[2], acc[3]);
            *(float4*)(part_dst + k0) = st;
        } else {
#pragma unroll
            for (int kkk = 0; kkk < 4; ++kkk)
                atomicAdd(&ws_kvec[k0 + kkk], acc[kkk]);
        }
    }
}

// Reduce NBLK x KCB partials into ws_kvec. Grid 256: block = (sb, kb),
// sb = 16 slabs of 32 blocks, kb = 16 slabs of 256 k's. 16 atomics per k.
__global__ void hs_reduce(const float* __restrict__ part, float* __restrict__ kvec)
{
    const int kb = blockIdx.x & 15;
    const int sb = blockIdx.x >> 4;
    const int k  = kb * 256 + threadIdx.x;
    const float* pp = part + (size_t)sb * 32 * KCB + k;
    float s = 0.f;
#pragma unroll 8
    for (int bb = 0; bb < 32; ++bb) s += pp[bb * KCB];
    atomicAdd(&kvec[k], s);
}

__global__ void hs_final(const float* __restrict__ ws_kvec,
                         const float* __restrict__ ws_scal,
                         float* __restrict__ out)
{
    __shared__ float red[4];
    const int tid = threadIdx.x;
    float local = 0.f;
    for (int k = tid; k < KCB; k += 256) {
        float a = ws_kvec[k] * (1.0f / 32768.0f);
        local += a * (log2f(a + 1e-15f) * LN2f);
    }
#pragma unroll
    for (int off = 1; off < 64; off <<= 1) local += __shfl_xor(local, off);
    if ((tid & 63) == 0) red[tid >> 6] = local;
    __syncthreads();
    if (tid == 0) {
        float mean_entro = -(red[0] + red[1] + red[2] + red[3]);
        float entro_mean = ws_scal[0] * (1.0f / 32768.0f);
        float commit     = ws_scal[1] * (1.0f / (32768.0f * 18.0f));
        out[SCL_OFF + 0] = entro_mean;
        out[SCL_OFF + 1] = mean_entro;
        out[SCL_OFF + 2] = entro_mean - mean_entro;
        out[SCL_OFF + 3] = commit;
    }
}

extern "C" void kernel_launch(void* const* d_in, const int* in_sizes, int n_in,
                              void* d_out, int out_size, void* d_ws, size_t ws_size,
                              hipStream_t stream)
{
    const float* x  = (const float*)d_in[0];
    const float* sp = (const float*)d_in[1];
    float* out = (float*)d_out;
    float* ws  = (float*)d_ws;

    const bool partials =
        ws_size >= (size_t)(WS_HDR + (size_t)NBLK * KCB) * sizeof(float);

    hipMemsetAsync(ws, 0, WS_HDR * sizeof(float), stream);

    hs_main<<<NBLK, 512, 0, stream>>>(x, sp, out + Q_OFF, out + IDX_OFF,
                                      ws, partials ? ws + WS_HDR : nullptr,
                                      ws + 2);
    if (partials)
        hs_reduce<<<256, 256, 0, stream>>>(ws + WS_HDR, ws + 2);
    hs_final<<<1, 256, 0, stream>>>(ws + 2, ws, out);
}